// Round 15
// baseline (93.899 us; speedup 1.0000x reference)
//
#include <hip/hip_runtime.h>
#include <hip/hip_bf16.h>
#include <stdint.h>

typedef __attribute__((ext_vector_type(8))) short short8;
typedef __attribute__((ext_vector_type(4))) float floatx4;
typedef __attribute__((ext_vector_type(4))) int intx4;

// ---------------------------------------------------------------------------
// Inter-kernel buffers in static device globals (r7/r9 proven). d_ws unused
// (r9: the harness's 40us/iter 256MB workspace fill runs unconditionally).
// r15: stage2's fused linear phase is SPLIT OFF into linear_kernel. stage2
// and stage1 are structural twins, yet stage1 ~5us / stage2 ~30us; the only
// asymmetry is stage2's per-wave tail: 60 shfl_xor (ds_bpermute, ~40cy,
// 6-deep serial chain), 30 W loads, flat_t round-trip, and same-line
// atomicAdds gating s_endpgm. Splitting removes that tail from all 5120
// waves and runs the linear ONCE (r0-verified code, no atomics at all).
// ---------------------------------------------------------------------------
__device__ float h_g[128 * 4056];            // 128 x 676 x 6 f32 (~2.08 MB)
__device__ float flat_g[128 * 6400];         // flat, padded stride (3.28 MB)
__device__ unsigned short bsw1_g[8192];      // stage-1 B fragments (16 KB)
__device__ unsigned short bsw2c_g[14400];    // stage-2 B frags COMPACT (28.8 KB)

// ---------------------------------------------------------------------------
// Threefry-2x32 (20 rounds), bit-exact vs JAX (verified r2: absmax 0.0).
// ---------------------------------------------------------------------------
__device__ __forceinline__ void threefry2x32(uint32_t k0, uint32_t k1,
                                             uint32_t& x0, uint32_t& x1) {
  const uint32_t ks2 = k0 ^ k1 ^ 0x1BD11BDAu;
  uint32_t ks[3] = {k0, k1, ks2};
  const int rot[8] = {13, 15, 26, 6, 17, 29, 16, 24};
  x0 += ks[0];
  x1 += ks[1];
#pragma unroll
  for (int i = 0; i < 5; ++i) {
#pragma unroll
    for (int j = 0; j < 4; ++j) {
      const int r = rot[(i & 1) * 4 + j];
      x0 += x1;
      x1 = (x1 << r) | (x1 >> (32 - r));
      x1 ^= x0;
    }
    x0 += ks[(i + 1) % 3];
    x1 += ks[(i + 2) % 3] + (uint32_t)(i + 1);
  }
}

// Compile-time fold: threefry(key=(0,42), data=(0,core)) — integer-exact.
struct TFPair { uint32_t x0, x1; };
constexpr TFPair tf_const(uint32_t k0, uint32_t k1, uint32_t x0, uint32_t x1) {
  const uint32_t ks2 = k0 ^ k1 ^ 0x1BD11BDAu;
  uint32_t ks[3] = {k0, k1, ks2};
  const int rot[8] = {13, 15, 26, 6, 17, 29, 16, 24};
  x0 += ks[0];
  x1 += ks[1];
  for (int i = 0; i < 5; ++i) {
    for (int j = 0; j < 4; ++j) {
      const int r = rot[(i & 1) * 4 + j];
      x0 += x1;
      x1 = (x1 << r) | (x1 >> (32 - r));
      x1 ^= x0;
    }
    x0 += ks[(i + 1) % 3];
    x1 += ks[(i + 2) % 3] + (uint32_t)(i + 1);
  }
  return {x0, x1};
}
constexpr TFPair FOLD0 = tf_const(0u, 42u, 0u, 0u);
constexpr TFPair FOLD1 = tf_const(0u, 42u, 0u, 1u);

__device__ __forceinline__ float dropmask(int core, int e, float v) {
  const uint32_t f0 = core ? FOLD1.x0 : FOLD0.x0;
  const uint32_t f1 = core ? FOLD1.x1 : FOLD0.x1;
  uint32_t a = 0u, b = (uint32_t)e;
  threefry2x32(f0, f1, a, b);
  uint32_t bits = a ^ b;
  float u = __uint_as_float((bits >> 9) | 0x3F800000u) - 1.0f;
  float m = (u < 0.8f) ? 1.0f : 0.0f;
  return v * m / 0.8f;
}

__device__ __forceinline__ unsigned short f2bf(float f) {  // RNE
  uint32_t u = __float_as_uint(f);
  uint32_t r = u + 0x7fffu + ((u >> 16) & 1u);
  return (unsigned short)(r >> 16);
}

union B2I { __hip_bfloat162 b; int i; };
__device__ __forceinline__ int pk_bf16(float lo, float hi) {
  B2I u;
  u.b = __float22bfloat162_rn(make_float2(lo, hi));
  return u.i;
}
union Frag { intx4 i; short8 s; };

// ---------------------------------------------------------------------------
// Prep: masked bf16 B matrices in MFMA B-fragment order (verified r3-r13).
// stage1: k = c*32+q*8+j (c<16, 64 lanes).
// stage2 COMPACT: s < 14400: j = s&7, wl = (s>>3)%40, c = (s>>3)/40;
//   o = wl%10, q = wl/10; t = 45q+c; m = t/5, nk = 8*(t%5)+j; zero if nk>=36.
// (out-init removed: linear_kernel writes out directly, no atomics.)
// ---------------------------------------------------------------------------
__global__ void prep_kernel(const float* __restrict__ eps0,
                            const float* __restrict__ eps1) {
  int idx = blockIdx.x * 256 + threadIdx.x;  // grid 89 blocks = 22784 threads
  if (idx < 8192) {
    int j = idx & 7, L = (idx >> 3) & 63, c = idx >> 9;
    int o = L & 15, q = L >> 4;
    int k = c * 32 + q * 8 + j;
    float v = 0.0f;
    if (o < 6) {
      int e = o * 512 + k;
      v = dropmask(0, e, eps0[e]);
    }
    bsw1_g[idx] = f2bf(v);
  } else if (idx < 22592) {
    int s = idx - 8192;  // < 14400 = 45*40*8
    int j = s & 7;
    int wl = (s >> 3) % 40;  // 0..39
    int c = (s >> 3) / 40;   // 0..44
    int o = wl % 10, q = wl / 10;
    int t = 45 * q + c;
    int m = t / 5, nk = 8 * (t % 5) + j;
    float v = 0.0f;
    if (nk < 36) {
      int e = o * 1296 + m * 36 + nk;
      v = dropmask(1, e, eps1[e]);
    }
    bsw2c_g[s] = f2bf(v);
  }
}

// ---------------------------------------------------------------------------
// Stage-1 kernel (r10 form, verified): barrier-free tiles, B1 frags in block
// LDS, launch_bounds(256,8) high occupancy. r1-verified math.
// ---------------------------------------------------------------------------
__global__ __launch_bounds__(256, 8) void stage1_kernel(
    const float* __restrict__ x) {
  __shared__ intx4 b1s[1024];  // 16 frags x 64 lanes, 16384 B

  const int b = blockIdx.y;
  const int tid = threadIdx.x;

  // stage bsw1 -> LDS (coalesced, 4 x 4KB passes)
  {
    const intx4* bsrc1 = (const intx4*)bsw1_g;
#pragma unroll
    for (int i = 0; i < 4; ++i) b1s[i * 256 + tid] = bsrc1[i * 256 + tid];
  }
  __syncthreads();  // before any divergent exit

  const int t1 = blockIdx.x * 4 + (tid >> 6);
  if (t1 >= 43) return;  // wave-uniform exit
  const int lane = tid & 63;
  const int col = lane & 15, q = lane >> 4;

  const float2* x2 = (const float2*)x + b * 784;  // 28*28 float2 per image
  const int p_raw = t1 * 16 + col;
  const int p = p_raw < 676 ? p_raw : 675;  // clamp for addressing
  const int ii = p / 26, jj = p - (p / 26) * 26;

  float xv[9][2];
#pragma unroll
  for (int di = 0; di < 3; ++di)
#pragma unroll
    for (int dj = 0; dj < 3; ++dj) {
      float2 v = x2[(ii + di) * 28 + (jj + dj)];
      xv[di * 3 + dj][0] = v.x;
      xv[di * 3 + dj][1] = v.y;
    }

  float w3[8];
#pragma unroll
  for (int j = 0; j < 8; ++j)
    w3[j] = xv[6][(j >> 2) & 1] * xv[7][(j >> 1) & 1] * xv[8][j & 1];

  const float wq = xv[4][(q >> 1) & 1] * xv[5][q & 1];
  float t01[4], t23[4];
#pragma unroll
  for (int a = 0; a < 2; ++a)
#pragma unroll
    for (int d = 0; d < 2; ++d) {
      t01[a * 2 + d] = xv[0][a] * xv[1][d];
      t23[a * 2 + d] = xv[2][a] * xv[3][d] * wq;
    }

  floatx4 acc0 = {0.f, 0.f, 0.f, 0.f};
  floatx4 acc1 = {0.f, 0.f, 0.f, 0.f};
#pragma unroll
  for (int c = 0; c < 16; ++c) {
    Frag bf;
    bf.i = b1s[c * 64 + lane];  // LDS at-use (conflict-free b128)
    const float w = t01[c >> 2] * t23[c & 3];
    Frag af;
    af.i.x = pk_bf16(w * w3[0], w * w3[1]);
    af.i.y = pk_bf16(w * w3[2], w * w3[3]);
    af.i.z = pk_bf16(w * w3[4], w * w3[5]);
    af.i.w = pk_bf16(w * w3[6], w * w3[7]);
    if (c & 1)
      acc1 = __builtin_amdgcn_mfma_f32_16x16x32_bf16(af.s, bf.s, acc1, 0, 0, 0);
    else
      acc0 = __builtin_amdgcn_mfma_f32_16x16x32_bf16(af.s, bf.s, acc0, 0, 0, 0);
  }
  const floatx4 acc = acc0 + acc1;
  if (col < 6) {
#pragma unroll
    for (int r = 0; r < 4; ++r) {
      const int pp = t1 * 16 + q * 4 + r;
      if (pp < 676) h_g[b * 4056 + pp * 6 + col] = acc[r];
    }
  }
}

// ---------------------------------------------------------------------------
// Stage-2 kernel — r14 form (8-wave blocks, compact b2s in LDS, 6 w/SIMD)
// MINUS the linear phase: after the MFMA loop each wave copies its 160
// contiguous flat floats to flat_g (padded image stride 6400 so tile 39's
// pixels 625..639 land in-bounds as zeros; f<6250 is all that linear reads).
// No shuffles, no W loads, no atomics in this kernel anymore.
// ---------------------------------------------------------------------------
__global__ __launch_bounds__(512, 6) void stage2_kernel(
    float* __restrict__ outdummy) {
  __shared__ intx4 b2s[1800];        // 45 chunks x 40 lanes, 28800 B
  __shared__ float hs[1092];         // up to 7 rows x 26 x 6
  __shared__ float flat_t[8][160];   // per-wave tile of flat

  const int b = blockIdx.y;
  const int tg = blockIdx.x;  // tile group 0..4 (8 tiles each)
  const int tid = threadIdx.x;
  const int wv = tid >> 6;    // 0..7
  const int lane = tid & 63;
  const int col = lane & 15, q = lane >> 4;
  const int colc = col < 10 ? col : 9;  // clamp: col>=10 dup feeds dead cols
  (void)outdummy;

  // ---- Stage compact bsw2c -> LDS (coalesced; shared by 8 waves) ----
  {
    const intx4* bsrc2g = (const intx4*)bsw2c_g;
#pragma unroll 1
    for (int i = tid; i < 1800; i += 512) b2s[i] = bsrc2g[i];
  }

  // ---- Stage h rows r_lo..r_lo+6 (clamped to 26) into LDS, coalesced ----
  const int r_lo = (tg * 128) / 25;
  const int nrow = (26 - r_lo) < 7 ? (26 - r_lo) : 7;
  const int nflt = nrow * 156;  // 156 = 26*6 floats per row
  for (int i = tid; i < nflt; i += 512) hs[i] = h_g[b * 4056 + r_lo * 156 + i];
  __syncthreads();  // the only barrier (covers b2s and hs)

  // ---- Stage 2: this wave's one 16-pixel tile ----
  const int tile = tg * 8 + wv;  // 0..39, all valid
  const int base2 = tile * 16;
  const int p_raw = base2 + col;
  const int p = p_raw < 625 ? p_raw : 624;  // clamp for addressing
  const int prow = (p * 41) >> 10;          // p/25 (exact for p < 1024)
  const int pcol = p - prow * 25;
  const int lr = prow - r_lo;               // 0..6 within staged rows
  const int hbase = (lr * 26 + pcol) * 6;

  // h10/h11 register-resident (12 VGPR); h00/h01 read at-use from LDS.
  float h10r[6], h11r[6];
#pragma unroll
  for (int t = 0; t < 6; ++t) {
    h10r[t] = hs[hbase + 156 + t];
    h11r[t] = hs[hbase + 162 + t];
  }

  floatx4 acc0 = {0.f, 0.f, 0.f, 0.f};
  floatx4 acc1 = {0.f, 0.f, 0.f, 0.f};
#pragma unroll
  for (int d = 0; d < 9; ++d) {  // chunk c = 5d + e; m = 9q + d
    const int m = 9 * q + d;
    const int ia = (m * 43) >> 8;  // m/6 exact for m < 54
    const int ic = m - ia * 6;
    const float p01 = hs[hbase + ia] * hs[hbase + 6 + ic];  // indexed LDS
    float ph[6];
#pragma unroll
    for (int a = 0; a < 6; ++a) ph[a] = p01 * h10r[a];
#pragma unroll
    for (int e = 0; e < 5; ++e) {
      Frag bf;
      bf.i = b2s[(d * 5 + e) * 40 + q * 10 + colc];  // LDS; dup=broadcast
      const int n0 = 8 * e;
      float av[8];
#pragma unroll
      for (int j = 0; j < 8; ++j) {
        const int n = n0 + j;  // compile-time after unroll
        av[j] = (n < 36) ? ph[n / 6] * h11r[n % 6] : 0.0f;
      }
      Frag af;
      af.i.x = pk_bf16(av[0], av[1]);
      af.i.y = pk_bf16(av[2], av[3]);
      af.i.z = pk_bf16(av[4], av[5]);
      af.i.w = pk_bf16(av[6], av[7]);
      if (e & 1)
        acc1 = __builtin_amdgcn_mfma_f32_16x16x32_bf16(af.s, bf.s, acc1, 0, 0, 0);
      else
        acc0 = __builtin_amdgcn_mfma_f32_16x16x32_bf16(af.s, bf.s, acc0, 0, 0, 0);
    }
  }
  const floatx4 acc = acc0 + acc1;

  // ---- Flat tile -> per-wave LDS (zero invalid pixels; all 160 set) ----
  if (col < 10) {
#pragma unroll
    for (int r = 0; r < 4; ++r) {
      const int lp = q * 4 + r;
      flat_t[wv][lp * 10 + col] = (base2 + lp < 625) ? acc[r] : 0.0f;
    }
  }
  // single-wave write->read: ordered by lgkmcnt, no barrier needed (r4)

  // ---- Coalesced copy: 160 contiguous floats -> flat_g (padded stride) ----
  float* dst = flat_g + b * 6400 + base2 * 10;
#pragma unroll
  for (int i = 0; i < 3; ++i) {
    const int f = i * 64 + lane;
    if (f < 160) dst[f] = flat_t[wv][f];
  }
}

// ---------------------------------------------------------------------------
// Linear kernel: out[b,:] = bias + flat[b,:] @ W^T. One 512-thr block per
// image; the EXACT r0/r1-verified code path (512-stride partials, 64-lane
// shfl reduce, cross-wave LDS reduce, direct store — no atomics).
// ---------------------------------------------------------------------------
__global__ __launch_bounds__(512, 4) void linear_kernel(
    const float* __restrict__ W, const float* __restrict__ bias,
    float* __restrict__ out) {
  __shared__ float red[8][10];
  const int b = blockIdx.x;
  const int tid = threadIdx.x;
  const int lane = tid & 63;
  const int wv = tid >> 6;

  const float* flat = flat_g + b * 6400;
  float acc[10];
#pragma unroll
  for (int o = 0; o < 10; ++o) acc[o] = 0.0f;
  for (int f = tid; f < 6250; f += 512) {
    const float v = flat[f];
#pragma unroll
    for (int o = 0; o < 10; ++o) acc[o] += v * W[o * 6250 + f];
  }
#pragma unroll
  for (int o = 0; o < 10; ++o) {
#pragma unroll
    for (int s = 32; s > 0; s >>= 1) acc[o] += __shfl_xor(acc[o], s, 64);
  }
  if (lane == 0) {
#pragma unroll
    for (int o = 0; o < 10; ++o) red[wv][o] = acc[o];
  }
  __syncthreads();
  if (tid < 10) {
    float r = bias[tid];
#pragma unroll
    for (int ww = 0; ww < 8; ++ww) r += red[ww][tid];
    out[b * 10 + tid] = r;
  }
}

// ---------------------------------------------------------------------------
extern "C" void kernel_launch(void* const* d_in, const int* in_sizes, int n_in,
                              void* d_out, int out_size, void* d_ws,
                              size_t ws_size, hipStream_t stream) {
  const float* x = (const float*)d_in[0];     // (128,28,28,2)
  const float* eps0 = (const float*)d_in[1];  // (6,512)
  const float* eps1 = (const float*)d_in[2];  // (10,1296)
  const float* W = (const float*)d_in[3];     // (10,6250)
  const float* bias = (const float*)d_in[4];  // (10,)
  float* out = (float*)d_out;                 // (128,10)
  (void)d_ws; (void)ws_size;  // workspace unused (r9: fill is unconditional)

  hipLaunchKernelGGL(prep_kernel, dim3(89), dim3(256), 0, stream, eps0, eps1);
  hipLaunchKernelGGL(stage1_kernel, dim3(11, 128), dim3(256), 0, stream, x);
  hipLaunchKernelGGL(stage2_kernel, dim3(5, 128), dim3(512), 0, stream, out);
  hipLaunchKernelGGL(linear_kernel, dim3(128), dim3(512), 0, stream, W, bias,
                     out);
}

// Round 16
// 92.849 us; speedup vs baseline: 1.0113x; 1.0113x over previous
//
#include <hip/hip_runtime.h>
#include <hip/hip_bf16.h>
#include <stdint.h>

typedef __attribute__((ext_vector_type(8))) short short8;
typedef __attribute__((ext_vector_type(4))) float floatx4;
typedef __attribute__((ext_vector_type(4))) int intx4;

// ---------------------------------------------------------------------------
// r16: TWO-launch pipeline (prep + merged). r15 measured a dispatch boundary
// at +4-6us and the h_g round-trip at ~1-2us; merging stage1 into stage2
// removes both. Each merged block recomputes its own 7 h rows into LDS
// (1.35x halo redundancy on the cheap phase — stage1 was only ~5us total).
// B1 (16KB) and compact B2 (28.8KB) are both read at-use from L1; they
// never coexist (phase-separated by the barrier) so each fits 32KB L1
// alone. r13 proved at-use-L1 == LDS-staged for B2. d_ws unused (r9: the
// 40us/iter 256MB workspace fill is unconditional harness cost).
// ---------------------------------------------------------------------------
__device__ unsigned short bsw1_g[8192];      // stage-1 B fragments (16 KB)
__device__ unsigned short bsw2c_g[14400];    // stage-2 B frags COMPACT (28.8 KB)

// ---------------------------------------------------------------------------
// Threefry-2x32 (20 rounds), bit-exact vs JAX (verified r2: absmax 0.0).
// ---------------------------------------------------------------------------
__device__ __forceinline__ void threefry2x32(uint32_t k0, uint32_t k1,
                                             uint32_t& x0, uint32_t& x1) {
  const uint32_t ks2 = k0 ^ k1 ^ 0x1BD11BDAu;
  uint32_t ks[3] = {k0, k1, ks2};
  const int rot[8] = {13, 15, 26, 6, 17, 29, 16, 24};
  x0 += ks[0];
  x1 += ks[1];
#pragma unroll
  for (int i = 0; i < 5; ++i) {
#pragma unroll
    for (int j = 0; j < 4; ++j) {
      const int r = rot[(i & 1) * 4 + j];
      x0 += x1;
      x1 = (x1 << r) | (x1 >> (32 - r));
      x1 ^= x0;
    }
    x0 += ks[(i + 1) % 3];
    x1 += ks[(i + 2) % 3] + (uint32_t)(i + 1);
  }
}

// Compile-time fold: threefry(key=(0,42), data=(0,core)) — integer-exact.
struct TFPair { uint32_t x0, x1; };
constexpr TFPair tf_const(uint32_t k0, uint32_t k1, uint32_t x0, uint32_t x1) {
  const uint32_t ks2 = k0 ^ k1 ^ 0x1BD11BDAu;
  uint32_t ks[3] = {k0, k1, ks2};
  const int rot[8] = {13, 15, 26, 6, 17, 29, 16, 24};
  x0 += ks[0];
  x1 += ks[1];
  for (int i = 0; i < 5; ++i) {
    for (int j = 0; j < 4; ++j) {
      const int r = rot[(i & 1) * 4 + j];
      x0 += x1;
      x1 = (x1 << r) | (x1 >> (32 - r));
      x1 ^= x0;
    }
    x0 += ks[(i + 1) % 3];
    x1 += ks[(i + 2) % 3] + (uint32_t)(i + 1);
  }
  return {x0, x1};
}
constexpr TFPair FOLD0 = tf_const(0u, 42u, 0u, 0u);
constexpr TFPair FOLD1 = tf_const(0u, 42u, 0u, 1u);

__device__ __forceinline__ float dropmask(int core, int e, float v) {
  const uint32_t f0 = core ? FOLD1.x0 : FOLD0.x0;
  const uint32_t f1 = core ? FOLD1.x1 : FOLD0.x1;
  uint32_t a = 0u, b = (uint32_t)e;
  threefry2x32(f0, f1, a, b);
  uint32_t bits = a ^ b;
  float u = __uint_as_float((bits >> 9) | 0x3F800000u) - 1.0f;
  float m = (u < 0.8f) ? 1.0f : 0.0f;
  return v * m / 0.8f;
}

__device__ __forceinline__ unsigned short f2bf(float f) {  // RNE
  uint32_t u = __float_as_uint(f);
  uint32_t r = u + 0x7fffu + ((u >> 16) & 1u);
  return (unsigned short)(r >> 16);
}

union B2I { __hip_bfloat162 b; int i; };
__device__ __forceinline__ int pk_bf16(float lo, float hi) {
  B2I u;
  u.b = __float22bfloat162_rn(make_float2(lo, hi));
  return u.i;
}
union Frag { intx4 i; short8 s; };

// ---------------------------------------------------------------------------
// Prep: masked bf16 B matrices in MFMA B-fragment order (verified r3-r13).
// stage1: k = c*32+q*8+j (c<16, 64 lanes).
// stage2 COMPACT: s < 14400: j = s&7, wl = (s>>3)%40, c = (s>>3)/40;
//   o = wl%10, q = wl/10; t = 45q+c; m = t/5, nk = 8*(t%5)+j; zero if nk>=36.
// ALSO: initializes out = bias (merged kernel accumulates via atomicAdd).
// ---------------------------------------------------------------------------
__global__ void prep_kernel(const float* __restrict__ eps0,
                            const float* __restrict__ eps1,
                            const float* __restrict__ bias,
                            float* __restrict__ out) {
  int idx = blockIdx.x * 256 + threadIdx.x;  // grid 89 blocks = 22784 threads
  if (idx < 1280) out[idx] = bias[idx % 10]; // (128,10) = bias init
  if (idx < 8192) {
    int j = idx & 7, L = (idx >> 3) & 63, c = idx >> 9;
    int o = L & 15, q = L >> 4;
    int k = c * 32 + q * 8 + j;
    float v = 0.0f;
    if (o < 6) {
      int e = o * 512 + k;
      v = dropmask(0, e, eps0[e]);
    }
    bsw1_g[idx] = f2bf(v);
  } else if (idx < 22592) {
    int s = idx - 8192;  // < 14400 = 45*40*8
    int j = s & 7;
    int wl = (s >> 3) % 40;  // 0..39
    int c = (s >> 3) / 40;   // 0..44
    int o = wl % 10, q = wl / 10;
    int t = 45 * q + c;
    int m = t / 5, nk = 8 * (t % 5) + j;
    float v = 0.0f;
    if (nk < 36) {
      int e = o * 1296 + m * 36 + nk;
      v = dropmask(1, e, eps1[e]);
    }
    bsw2c_g[s] = f2bf(v);
  }
}

// ---------------------------------------------------------------------------
// Merged kernel: grid (5,128) x 512 thr (8 waves), 5120 waves = exactly
// 5/SIMD in one co-resident round (launch_bounds(512,5), r11-proven best).
// Phase 1 (stage1): block computes h rows r_lo..r_lo+nrow-1 (nrow<=7) into
//   hs LDS. Pixel span [r_lo*26, r_lo*26+nrow*26), <=12 tiles of 16,
//   wave-strided. B1 frags at-use from L1-resident bsw1_g. Per-tile math =
//   the r1-verified sequence (bit-identical h values).
// __syncthreads (the only barrier).
// Phase 2 (stage2+linear): r13-exact — at-use compact B2 (L1-resident),
//   reg-diet h access, per-wave flat_t, 160-wide linear partial vs W slice,
//   10 lane-spread atomicAdds into out (pre-set to bias by prep).
// Row coverage verified per tg: stage2 tiles of group tg need h rows
//   prow..prow+1 <= r_lo+6 for tg<4 and <= 25 for tg=4. ✓
// ---------------------------------------------------------------------------
__global__ __launch_bounds__(512, 5) void merged_kernel(
    const float* __restrict__ x, const float* __restrict__ W,
    float* __restrict__ out) {
  __shared__ float hs[1092];         // up to 7 rows x 26 x 6
  __shared__ float flat_t[8][160];   // per-wave tile of flat

  const int b = blockIdx.y;
  const int tg = blockIdx.x;  // tile group 0..4 (8 stage2-tiles each)
  const int tid = threadIdx.x;
  const int wv = tid >> 6;    // 0..7
  const int lane = tid & 63;
  const int col = lane & 15, q = lane >> 4;

  const int r_lo = (tg * 128) / 25;
  const int nrow = (26 - r_lo) < 7 ? (26 - r_lo) : 7;
  const int pbase = r_lo * 26;          // first h pixel of the span
  const int nspan = nrow * 26;          // 156 or 182 pixels
  const int ntiles1 = (nspan + 15) >> 4;  // 10 or 12

  // ==== Phase 1: compute this block's h span into hs ====
  const float2* x2 = (const float2*)x + b * 784;  // 28*28 float2 per image
  const intx4* bsrc1 = (const intx4*)bsw1_g;
#pragma unroll 1
  for (int t1 = wv; t1 < ntiles1; t1 += 8) {
    const int pl_raw = t1 * 16 + col;
    const int pl = pl_raw < nspan ? pl_raw : nspan - 1;  // clamp (addressing)
    const int p = pbase + pl;             // global h pixel < 676
    const int ii = p / 26, jj = p - (p / 26) * 26;

    float xv[9][2];
#pragma unroll
    for (int di = 0; di < 3; ++di)
#pragma unroll
      for (int dj = 0; dj < 3; ++dj) {
        float2 v = x2[(ii + di) * 28 + (jj + dj)];
        xv[di * 3 + dj][0] = v.x;
        xv[di * 3 + dj][1] = v.y;
      }

    float w3[8];
#pragma unroll
    for (int j = 0; j < 8; ++j)
      w3[j] = xv[6][(j >> 2) & 1] * xv[7][(j >> 1) & 1] * xv[8][j & 1];

    const float wq = xv[4][(q >> 1) & 1] * xv[5][q & 1];
    float t01[4], t23[4];
#pragma unroll
    for (int a = 0; a < 2; ++a)
#pragma unroll
      for (int d = 0; d < 2; ++d) {
        t01[a * 2 + d] = xv[0][a] * xv[1][d];
        t23[a * 2 + d] = xv[2][a] * xv[3][d] * wq;
      }

    floatx4 acc0 = {0.f, 0.f, 0.f, 0.f};
    floatx4 acc1 = {0.f, 0.f, 0.f, 0.f};
#pragma unroll
    for (int c = 0; c < 16; ++c) {
      Frag bf;
      bf.i = bsrc1[c * 64 + lane];  // at-use; bsw1 is L1-resident (16 KB)
      const float w = t01[c >> 2] * t23[c & 3];
      Frag af;
      af.i.x = pk_bf16(w * w3[0], w * w3[1]);
      af.i.y = pk_bf16(w * w3[2], w * w3[3]);
      af.i.z = pk_bf16(w * w3[4], w * w3[5]);
      af.i.w = pk_bf16(w * w3[6], w * w3[7]);
      if (c & 1)
        acc1 = __builtin_amdgcn_mfma_f32_16x16x32_bf16(af.s, bf.s, acc1, 0, 0, 0);
      else
        acc0 = __builtin_amdgcn_mfma_f32_16x16x32_bf16(af.s, bf.s, acc0, 0, 0, 0);
    }
    const floatx4 acc = acc0 + acc1;
    if (col < 6) {
#pragma unroll
      for (int r = 0; r < 4; ++r) {
        const int ppl = t1 * 16 + q * 4 + r;
        if (ppl < nspan) hs[ppl * 6 + col] = acc[r];
      }
    }
  }
  __syncthreads();  // the only barrier: hs complete

  // ==== Phase 2: stage2 tile + inline linear (r13/r14-exact) ====
  const int colc = col < 10 ? col : 9;  // clamp: col>=10 dup feeds dead cols
  const int tile = tg * 8 + wv;  // 0..39, all valid
  const int base2 = tile * 16;
  const int p_raw = base2 + col;
  const int p = p_raw < 625 ? p_raw : 624;  // clamp for addressing
  const int prow = (p * 41) >> 10;          // p/25 (exact for p < 1024)
  const int pcol = p - prow * 25;
  const int lr = prow - r_lo;               // 0..6 within staged rows
  const int hbase = (lr * 26 + pcol) * 6;

  // h10/h11 register-resident (12 VGPR); h00/h01 read at-use from LDS.
  float h10r[6], h11r[6];
#pragma unroll
  for (int t = 0; t < 6; ++t) {
    h10r[t] = hs[hbase + 156 + t];
    h11r[t] = hs[hbase + 162 + t];
  }

  const intx4* bsrc2 = (const intx4*)bsw2c_g;  // compact: 40 intx4/chunk
  floatx4 acc0 = {0.f, 0.f, 0.f, 0.f};
  floatx4 acc1 = {0.f, 0.f, 0.f, 0.f};
#pragma unroll
  for (int d = 0; d < 9; ++d) {  // chunk c = 5d + e; m = 9q + d
    const int m = 9 * q + d;
    const int ia = (m * 43) >> 8;  // m/6 exact for m < 54
    const int ic = m - ia * 6;
    const float p01 = hs[hbase + ia] * hs[hbase + 6 + ic];  // indexed LDS
    float ph[6];
#pragma unroll
    for (int a = 0; a < 6; ++a) ph[a] = p01 * h10r[a];
#pragma unroll
    for (int e = 0; e < 5; ++e) {
      Frag bf;
      bf.i = bsrc2[(d * 5 + e) * 40 + q * 10 + colc];  // L1-resident compact
      const int n0 = 8 * e;
      float av[8];
#pragma unroll
      for (int j = 0; j < 8; ++j) {
        const int n = n0 + j;  // compile-time after unroll
        av[j] = (n < 36) ? ph[n / 6] * h11r[n % 6] : 0.0f;
      }
      Frag af;
      af.i.x = pk_bf16(av[0], av[1]);
      af.i.y = pk_bf16(av[2], av[3]);
      af.i.z = pk_bf16(av[4], av[5]);
      af.i.w = pk_bf16(av[6], av[7]);
      if (e & 1)
        acc1 = __builtin_amdgcn_mfma_f32_16x16x32_bf16(af.s, bf.s, acc1, 0, 0, 0);
      else
        acc0 = __builtin_amdgcn_mfma_f32_16x16x32_bf16(af.s, bf.s, acc0, 0, 0, 0);
    }
  }
  const floatx4 acc = acc0 + acc1;

  // ---- Flat tile -> per-wave LDS (zero invalid pixels; all 160 set) ----
  if (col < 10) {
#pragma unroll
    for (int r = 0; r < 4; ++r) {
      const int lp = q * 4 + r;
      flat_t[wv][lp * 10 + col] = (base2 + lp < 625) ? acc[r] : 0.0f;
    }
  }
  // single-wave write->read: ordered by lgkmcnt, no barrier needed (r4)

  // ---- Linear partial: this tile's 160 flat values vs W slice ----
  float a10[10];
#pragma unroll
  for (int o = 0; o < 10; ++o) a10[o] = 0.0f;
#pragma unroll
  for (int fi = 0; fi < 3; ++fi) {
    const int f = fi * 64 + lane;
    if (f < 160) {
      const float v = flat_t[wv][f];
      int gf = base2 * 10 + f;
      gf = gf < 6250 ? gf : 6249;  // clamp addr; v==0 there kills contribution
#pragma unroll
      for (int o = 0; o < 10; ++o) a10[o] += v * W[o * 6250 + gf];
    }
  }
#pragma unroll
  for (int o = 0; o < 10; ++o) {
#pragma unroll
    for (int s = 32; s > 0; s >>= 1) a10[o] += __shfl_xor(a10[o], s, 64);
  }
  float myv = a10[0];
#pragma unroll
  for (int o = 1; o < 10; ++o) myv = (lane == o) ? a10[o] : myv;
  if (lane < 10) atomicAdd(&out[b * 10 + lane], myv);
}

// ---------------------------------------------------------------------------
extern "C" void kernel_launch(void* const* d_in, const int* in_sizes, int n_in,
                              void* d_out, int out_size, void* d_ws,
                              size_t ws_size, hipStream_t stream) {
  const float* x = (const float*)d_in[0];     // (128,28,28,2)
  const float* eps0 = (const float*)d_in[1];  // (6,512)
  const float* eps1 = (const float*)d_in[2];  // (10,1296)
  const float* W = (const float*)d_in[3];     // (10,6250)
  const float* bias = (const float*)d_in[4];  // (10,)
  float* out = (float*)d_out;                 // (128,10)
  (void)d_ws; (void)ws_size;  // workspace unused (r9: fill is unconditional)

  hipLaunchKernelGGL(prep_kernel, dim3(89), dim3(256), 0, stream, eps0, eps1,
                     bias, out);
  hipLaunchKernelGGL(merged_kernel, dim3(5, 128), dim3(512), 0, stream, x, W,
                     out);
}

// Round 17
// 87.860 us; speedup vs baseline: 1.0687x; 1.0568x over previous
//
#include <hip/hip_runtime.h>
#include <hip/hip_bf16.h>
#include <stdint.h>

typedef __attribute__((ext_vector_type(8))) short short8;
typedef __attribute__((ext_vector_type(4))) float floatx4;
typedef __attribute__((ext_vector_type(4))) int intx4;

// ---------------------------------------------------------------------------
// r17 = exact revert to r14, the measured-best configuration (88.0 us, and
// fastest clock-normalized ~85). The round ledger: r15 (split linear) +6,
// r16 (merged stage1/2) +4 — every departure from this base regressed.
// Inter-kernel buffers in static device globals (r7/r9 proven). d_ws unused
// (r9: the harness's 40us/iter 256MB workspace fill runs unconditionally).
// bsw2 stored COMPACT (r13): 45 chunks x 40 lanes x 8 bf16 = 28.8 KB.
// stage2 uses BOTH proven levers: waves/SIMD (r11) + LDS-resident B2 (r12)
// via the compact layout: 8-wave blocks share one 28.8KB staged copy at
// 38.3KB/block -> 3 blocks/CU -> 6 waves/SIMD AND ds_read-speed B2.
// ---------------------------------------------------------------------------
__device__ float h_g[128 * 4056];            // 128 x 676 x 6 f32 (~2.08 MB)
__device__ unsigned short bsw1_g[8192];      // stage-1 B fragments (16 KB)
__device__ unsigned short bsw2c_g[14400];    // stage-2 B frags COMPACT (28.8 KB)

// ---------------------------------------------------------------------------
// Threefry-2x32 (20 rounds), bit-exact vs JAX (verified r2: absmax 0.0).
// ---------------------------------------------------------------------------
__device__ __forceinline__ void threefry2x32(uint32_t k0, uint32_t k1,
                                             uint32_t& x0, uint32_t& x1) {
  const uint32_t ks2 = k0 ^ k1 ^ 0x1BD11BDAu;
  uint32_t ks[3] = {k0, k1, ks2};
  const int rot[8] = {13, 15, 26, 6, 17, 29, 16, 24};
  x0 += ks[0];
  x1 += ks[1];
#pragma unroll
  for (int i = 0; i < 5; ++i) {
#pragma unroll
    for (int j = 0; j < 4; ++j) {
      const int r = rot[(i & 1) * 4 + j];
      x0 += x1;
      x1 = (x1 << r) | (x1 >> (32 - r));
      x1 ^= x0;
    }
    x0 += ks[(i + 1) % 3];
    x1 += ks[(i + 2) % 3] + (uint32_t)(i + 1);
  }
}

// Compile-time fold: threefry(key=(0,42), data=(0,core)) — integer-exact.
struct TFPair { uint32_t x0, x1; };
constexpr TFPair tf_const(uint32_t k0, uint32_t k1, uint32_t x0, uint32_t x1) {
  const uint32_t ks2 = k0 ^ k1 ^ 0x1BD11BDAu;
  uint32_t ks[3] = {k0, k1, ks2};
  const int rot[8] = {13, 15, 26, 6, 17, 29, 16, 24};
  x0 += ks[0];
  x1 += ks[1];
  for (int i = 0; i < 5; ++i) {
    for (int j = 0; j < 4; ++j) {
      const int r = rot[(i & 1) * 4 + j];
      x0 += x1;
      x1 = (x1 << r) | (x1 >> (32 - r));
      x1 ^= x0;
    }
    x0 += ks[(i + 1) % 3];
    x1 += ks[(i + 2) % 3] + (uint32_t)(i + 1);
  }
  return {x0, x1};
}
constexpr TFPair FOLD0 = tf_const(0u, 42u, 0u, 0u);
constexpr TFPair FOLD1 = tf_const(0u, 42u, 0u, 1u);

__device__ __forceinline__ float dropmask(int core, int e, float v) {
  const uint32_t f0 = core ? FOLD1.x0 : FOLD0.x0;
  const uint32_t f1 = core ? FOLD1.x1 : FOLD0.x1;
  uint32_t a = 0u, b = (uint32_t)e;
  threefry2x32(f0, f1, a, b);
  uint32_t bits = a ^ b;
  float u = __uint_as_float((bits >> 9) | 0x3F800000u) - 1.0f;
  float m = (u < 0.8f) ? 1.0f : 0.0f;
  return v * m / 0.8f;
}

__device__ __forceinline__ unsigned short f2bf(float f) {  // RNE
  uint32_t u = __float_as_uint(f);
  uint32_t r = u + 0x7fffu + ((u >> 16) & 1u);
  return (unsigned short)(r >> 16);
}

union B2I { __hip_bfloat162 b; int i; };
__device__ __forceinline__ int pk_bf16(float lo, float hi) {
  B2I u;
  u.b = __float22bfloat162_rn(make_float2(lo, hi));
  return u.i;
}
union Frag { intx4 i; short8 s; };

// ---------------------------------------------------------------------------
// Prep: masked bf16 B matrices in MFMA B-fragment order (verified r3-r13).
// stage1: k = c*32+q*8+j (c<16, 64 lanes).
// stage2 COMPACT: s < 14400: j = s&7, wl = (s>>3)%40, c = (s>>3)/40;
//   o = wl%10, q = wl/10; t = 45q+c; m = t/5, nk = 8*(t%5)+j; zero if nk>=36.
// ALSO: initializes out = bias (stage2 accumulates via atomicAdd).
// ---------------------------------------------------------------------------
__global__ void prep_kernel(const float* __restrict__ eps0,
                            const float* __restrict__ eps1,
                            const float* __restrict__ bias,
                            float* __restrict__ out) {
  int idx = blockIdx.x * 256 + threadIdx.x;  // grid 89 blocks = 22784 threads
  if (idx < 1280) out[idx] = bias[idx % 10]; // (128,10) = bias init
  if (idx < 8192) {
    int j = idx & 7, L = (idx >> 3) & 63, c = idx >> 9;
    int o = L & 15, q = L >> 4;
    int k = c * 32 + q * 8 + j;
    float v = 0.0f;
    if (o < 6) {
      int e = o * 512 + k;
      v = dropmask(0, e, eps0[e]);
    }
    bsw1_g[idx] = f2bf(v);
  } else if (idx < 22592) {
    int s = idx - 8192;  // < 14400 = 45*40*8
    int j = s & 7;
    int wl = (s >> 3) % 40;  // 0..39
    int c = (s >> 3) / 40;   // 0..44
    int o = wl % 10, q = wl / 10;
    int t = 45 * q + c;
    int m = t / 5, nk = 8 * (t % 5) + j;
    float v = 0.0f;
    if (nk < 36) {
      int e = o * 1296 + m * 36 + nk;
      v = dropmask(1, e, eps1[e]);
    }
    bsw2c_g[s] = f2bf(v);
  }
}

// ---------------------------------------------------------------------------
// Stage-1 kernel (r10 form, verified): barrier-free tiles, B1 frags in block
// LDS, launch_bounds(256,8) high occupancy. r1-verified math.
// ---------------------------------------------------------------------------
__global__ __launch_bounds__(256, 8) void stage1_kernel(
    const float* __restrict__ x) {
  __shared__ intx4 b1s[1024];  // 16 frags x 64 lanes, 16384 B

  const int b = blockIdx.y;
  const int tid = threadIdx.x;

  // stage bsw1 -> LDS (coalesced, 4 x 4KB passes)
  {
    const intx4* bsrc1 = (const intx4*)bsw1_g;
#pragma unroll
    for (int i = 0; i < 4; ++i) b1s[i * 256 + tid] = bsrc1[i * 256 + tid];
  }
  __syncthreads();  // before any divergent exit

  const int t1 = blockIdx.x * 4 + (tid >> 6);
  if (t1 >= 43) return;  // wave-uniform exit
  const int lane = tid & 63;
  const int col = lane & 15, q = lane >> 4;

  const float2* x2 = (const float2*)x + b * 784;  // 28*28 float2 per image
  const int p_raw = t1 * 16 + col;
  const int p = p_raw < 676 ? p_raw : 675;  // clamp for addressing
  const int ii = p / 26, jj = p - (p / 26) * 26;

  float xv[9][2];
#pragma unroll
  for (int di = 0; di < 3; ++di)
#pragma unroll
    for (int dj = 0; dj < 3; ++dj) {
      float2 v = x2[(ii + di) * 28 + (jj + dj)];
      xv[di * 3 + dj][0] = v.x;
      xv[di * 3 + dj][1] = v.y;
    }

  float w3[8];
#pragma unroll
  for (int j = 0; j < 8; ++j)
    w3[j] = xv[6][(j >> 2) & 1] * xv[7][(j >> 1) & 1] * xv[8][j & 1];

  const float wq = xv[4][(q >> 1) & 1] * xv[5][q & 1];
  float t01[4], t23[4];
#pragma unroll
  for (int a = 0; a < 2; ++a)
#pragma unroll
    for (int d = 0; d < 2; ++d) {
      t01[a * 2 + d] = xv[0][a] * xv[1][d];
      t23[a * 2 + d] = xv[2][a] * xv[3][d] * wq;
    }

  floatx4 acc0 = {0.f, 0.f, 0.f, 0.f};
  floatx4 acc1 = {0.f, 0.f, 0.f, 0.f};
#pragma unroll
  for (int c = 0; c < 16; ++c) {
    Frag bf;
    bf.i = b1s[c * 64 + lane];  // LDS at-use (conflict-free b128)
    const float w = t01[c >> 2] * t23[c & 3];
    Frag af;
    af.i.x = pk_bf16(w * w3[0], w * w3[1]);
    af.i.y = pk_bf16(w * w3[2], w * w3[3]);
    af.i.z = pk_bf16(w * w3[4], w * w3[5]);
    af.i.w = pk_bf16(w * w3[6], w * w3[7]);
    if (c & 1)
      acc1 = __builtin_amdgcn_mfma_f32_16x16x32_bf16(af.s, bf.s, acc1, 0, 0, 0);
    else
      acc0 = __builtin_amdgcn_mfma_f32_16x16x32_bf16(af.s, bf.s, acc0, 0, 0, 0);
  }
  const floatx4 acc = acc0 + acc1;
  if (col < 6) {
#pragma unroll
    for (int r = 0; r < 4; ++r) {
      const int pp = t1 * 16 + q * 4 + r;
      if (pp < 676) h_g[b * 4056 + pp * 6 + col] = acc[r];
    }
  }
}

// ---------------------------------------------------------------------------
// Stage-2 + linear kernel — r14 form (measured best): 512-thr/8-wave
// blocks, 8 tiles per block, grid (5,128) = 640 blocks. Compact bsw2c
// (28.8 KB) staged to LDS ONCE per block, shared by 8 waves; hs stages the
// block's 7 h rows. LDS 38.3 KB -> 3 blocks/CU -> 6 waves/SIMD on critical
// CUs AND ds_read-speed B2. One barrier; waves then fully independent.
// ---------------------------------------------------------------------------
__global__ __launch_bounds__(512, 6) void stage2_kernel(
    const float* __restrict__ W, float* __restrict__ out) {
  __shared__ intx4 b2s[1800];        // 45 chunks x 40 lanes, 28800 B
  __shared__ float hs[1092];         // up to 7 rows x 26 x 6
  __shared__ float flat_t[8][160];   // per-wave tile of flat

  const int b = blockIdx.y;
  const int tg = blockIdx.x;  // tile group 0..4 (8 tiles each)
  const int tid = threadIdx.x;
  const int wv = tid >> 6;    // 0..7
  const int lane = tid & 63;
  const int col = lane & 15, q = lane >> 4;
  const int colc = col < 10 ? col : 9;  // clamp: col>=10 dup feeds dead cols

  // ---- Stage compact bsw2c -> LDS (coalesced; shared by 8 waves) ----
  {
    const intx4* bsrc2g = (const intx4*)bsw2c_g;
#pragma unroll 1
    for (int i = tid; i < 1800; i += 512) b2s[i] = bsrc2g[i];
  }

  // ---- Stage h rows r_lo..r_lo+6 (clamped to 26) into LDS, coalesced ----
  const int r_lo = (tg * 128) / 25;
  const int nrow = (26 - r_lo) < 7 ? (26 - r_lo) : 7;
  const int nflt = nrow * 156;  // 156 = 26*6 floats per row
  for (int i = tid; i < nflt; i += 512) hs[i] = h_g[b * 4056 + r_lo * 156 + i];
  __syncthreads();  // the only barrier (covers b2s and hs)

  // ---- Stage 2: this wave's one 16-pixel tile ----
  const int tile = tg * 8 + wv;  // 0..39, all valid
  const int base2 = tile * 16;
  const int p_raw = base2 + col;
  const int p = p_raw < 625 ? p_raw : 624;  // clamp for addressing
  const int prow = (p * 41) >> 10;          // p/25 (exact for p < 1024)
  const int pcol = p - prow * 25;
  const int lr = prow - r_lo;               // 0..6 within staged rows
  const int hbase = (lr * 26 + pcol) * 6;

  // h10/h11 register-resident (12 VGPR); h00/h01 read at-use from LDS.
  float h10r[6], h11r[6];
#pragma unroll
  for (int t = 0; t < 6; ++t) {
    h10r[t] = hs[hbase + 156 + t];
    h11r[t] = hs[hbase + 162 + t];
  }

  floatx4 acc0 = {0.f, 0.f, 0.f, 0.f};
  floatx4 acc1 = {0.f, 0.f, 0.f, 0.f};
#pragma unroll
  for (int d = 0; d < 9; ++d) {  // chunk c = 5d + e; m = 9q + d
    const int m = 9 * q + d;
    const int ia = (m * 43) >> 8;  // m/6 exact for m < 54
    const int ic = m - ia * 6;
    const float p01 = hs[hbase + ia] * hs[hbase + 6 + ic];  // indexed LDS
    float ph[6];
#pragma unroll
    for (int a = 0; a < 6; ++a) ph[a] = p01 * h10r[a];
#pragma unroll
    for (int e = 0; e < 5; ++e) {
      Frag bf;
      bf.i = b2s[(d * 5 + e) * 40 + q * 10 + colc];  // LDS; dup=broadcast
      const int n0 = 8 * e;
      float av[8];
#pragma unroll
      for (int j = 0; j < 8; ++j) {
        const int n = n0 + j;  // compile-time after unroll
        av[j] = (n < 36) ? ph[n / 6] * h11r[n % 6] : 0.0f;
      }
      Frag af;
      af.i.x = pk_bf16(av[0], av[1]);
      af.i.y = pk_bf16(av[2], av[3]);
      af.i.z = pk_bf16(av[4], av[5]);
      af.i.w = pk_bf16(av[6], av[7]);
      if (e & 1)
        acc1 = __builtin_amdgcn_mfma_f32_16x16x32_bf16(af.s, bf.s, acc1, 0, 0, 0);
      else
        acc0 = __builtin_amdgcn_mfma_f32_16x16x32_bf16(af.s, bf.s, acc0, 0, 0, 0);
    }
  }
  const floatx4 acc = acc0 + acc1;

  // ---- Flat tile -> per-wave LDS (zero invalid pixels; all 160 set) ----
  if (col < 10) {
#pragma unroll
    for (int r = 0; r < 4; ++r) {
      const int lp = q * 4 + r;
      flat_t[wv][lp * 10 + col] = (base2 + lp < 625) ? acc[r] : 0.0f;
    }
  }
  // single-wave write->read: ordered by lgkmcnt, no barrier needed (r4)

  // ---- Linear partial: this tile's 160 flat values vs W slice ----
  float a10[10];
#pragma unroll
  for (int o = 0; o < 10; ++o) a10[o] = 0.0f;
#pragma unroll
  for (int fi = 0; fi < 3; ++fi) {
    const int f = fi * 64 + lane;
    if (f < 160) {
      const float v = flat_t[wv][f];
      int gf = base2 * 10 + f;
      gf = gf < 6250 ? gf : 6249;  // clamp addr; v==0 there kills contribution
#pragma unroll
      for (int o = 0; o < 10; ++o) a10[o] += v * W[o * 6250 + gf];
    }
  }
#pragma unroll
  for (int o = 0; o < 10; ++o) {
#pragma unroll
    for (int s = 32; s > 0; s >>= 1) a10[o] += __shfl_xor(a10[o], s, 64);
  }
  float myv = a10[0];
#pragma unroll
  for (int o = 1; o < 10; ++o) myv = (lane == o) ? a10[o] : myv;
  if (lane < 10) atomicAdd(&out[b * 10 + lane], myv);
}

// ---------------------------------------------------------------------------
extern "C" void kernel_launch(void* const* d_in, const int* in_sizes, int n_in,
                              void* d_out, int out_size, void* d_ws,
                              size_t ws_size, hipStream_t stream) {
  const float* x = (const float*)d_in[0];     // (128,28,28,2)
  const float* eps0 = (const float*)d_in[1];  // (6,512)
  const float* eps1 = (const float*)d_in[2];  // (10,1296)
  const float* W = (const float*)d_in[3];     // (10,6250)
  const float* bias = (const float*)d_in[4];  // (10,)
  float* out = (float*)d_out;                 // (128,10)
  (void)d_ws; (void)ws_size;  // workspace unused (r9: fill is unconditional)

  hipLaunchKernelGGL(prep_kernel, dim3(89), dim3(256), 0, stream, eps0, eps1,
                     bias, out);
  hipLaunchKernelGGL(stage1_kernel, dim3(11, 128), dim3(256), 0, stream, x);
  hipLaunchKernelGGL(stage2_kernel, dim3(5, 128), dim3(512), 0, stream, W,
                     out);
}